// Round 8
// baseline (195.639 us; speedup 1.0000x reference)
//
#include <hip/hip_runtime.h>

#define HW_N 1048576
#define C_IN 64
#define K_CLS 4096
#define H1_N 256
#define NCLS_N 16
#define SCAT_BLOCKS 64
#define ROWS_PER_SCAT (HW_N / SCAT_BLOCKS)  // 16384
#define CAP 512                              // slots per cluster (max n ~ 320)

__device__ __forceinline__ float silu_f(float x) {
  return x / (1.0f + expf(-x));
}

// Degree-3 B-spline bases on the uniform grid g[j] = 0.4*(j-3) - 1, j=0..11.
__device__ __forceinline__ void bspline8(float x, float* b) {
  float t[11];
#pragma unroll
  for (int j = 0; j < 11; ++j) {
    float g0 = 0.4f * (float)(j - 3) - 1.0f;
    float g1 = 0.4f * (float)(j - 2) - 1.0f;
    t[j] = (x >= g0 && x < g1) ? 1.0f : 0.0f;
  }
#pragma unroll
  for (int k = 1; k <= 3; ++k) {
#pragma unroll 10
    for (int j = 0; j + k < 11; ++j) {
      float gj   = 0.4f * (float)(j - 3) - 1.0f;
      float gj1  = 0.4f * (float)(j - 2) - 1.0f;
      float gjk  = 0.4f * (float)(j + k - 3) - 1.0f;
      float gjk1 = 0.4f * (float)(j + k - 2) - 1.0f;
      float left  = (x - gj) / (gjk - gj);
      float right = (gjk1 - x) / (gjk1 - gj1);
      t[j] = left * t[j] + right * t[j + 1];
    }
  }
#pragma unroll
  for (int g = 0; g < 8; ++g) b[g] = t[g];
}

// ---- Fused weight transposes (pre-scaled by spline_scaler) ----
// blocks 0..63:   swt1[i][o][e] = sw1[o][i][e]*sc1[o][i]; bwt1[i][o] = bw1[o][i]
// blocks 64..191: swt2[gi][o][e] = sw2[o][gi][e]*sc2[o][gi]; bwt2[gi][o] = bw2[o][gi]
__global__ __launch_bounds__(256) void transpose_w(
    const float* __restrict__ bw1, const float* __restrict__ sw1,
    const float* __restrict__ sc1, const float* __restrict__ bw2,
    const float* __restrict__ sw2, const float* __restrict__ sc2,
    float* __restrict__ bwt1, float* __restrict__ swt1,
    float* __restrict__ bwt2, float* __restrict__ swt2) {
  int bid = blockIdx.x, tid = threadIdx.x;
  if (bid < C_IN) {
    int i = bid, o = tid;
    float sc = sc1[o * C_IN + i];
    bwt1[i * H1_N + o] = bw1[o * C_IN + i];
    const float4* src = (const float4*)&sw1[(size_t)(o * C_IN + i) * 8];
    float4 a = src[0], b = src[1];
    a.x *= sc; a.y *= sc; a.z *= sc; a.w *= sc;
    b.x *= sc; b.y *= sc; b.z *= sc; b.w *= sc;
    float4* dst = (float4*)&swt1[(size_t)(i * H1_N + o) * 8];
    dst[0] = a; dst[1] = b;
  } else {
    int gi = (bid - C_IN) * 2 + (tid >> 7);
    int t = tid & 127;
    int o = t >> 3, e = t & 7;
    swt2[(gi * NCLS_N + o) * 8 + e] =
        sw2[(size_t)(o * H1_N + gi) * 8 + e] * sc2[o * H1_N + gi];
    if (t < NCLS_N) bwt2[gi * NCLS_N + t] = bw2[t * H1_N + gi];
  }
}

// ---- Scatter: block-aggregated atomic slot reservation ----
// Pass 1: LDS histogram of this block's 16384 rows.
// Reserve: one global atomicAdd per nonzero cluster -> base within cluster.
// Pass 2: place rows at spk[c*CAP + base + rank].  ccnt ends as cnt[c].
__global__ __launch_bounds__(1024) void scatter_atomic(
    const int* __restrict__ cls, int* __restrict__ ccnt,
    int* __restrict__ spk) {
  __shared__ int lhist[K_CLS];  // 16 KB
  int b = blockIdx.x, tid = threadIdx.x;
  for (int c = tid; c < K_CLS; c += 1024) lhist[c] = 0;
  __syncthreads();
  int r0 = b * ROWS_PER_SCAT;
  for (int r = r0 + tid; r < r0 + ROWS_PER_SCAT; r += 1024)
    atomicAdd(&lhist[cls[r]], 1);
  __syncthreads();
  for (int c = tid; c < K_CLS; c += 1024) {
    int n = lhist[c];
    lhist[c] = n ? atomicAdd(&ccnt[c], n) : 0;
  }
  __syncthreads();
  for (int r = r0 + tid; r < r0 + ROWS_PER_SCAT; r += 1024) {
    int c = cls[r];
    int pos = atomicAdd(&lhist[c], 1);
    spk[(size_t)c * CAP + pos] = r;
  }
}

// ---- Gather rows, register-accumulate -> mean ----
// One block per cluster. Thread (g,q) = (tid>>4, tid&15) accumulates float4
// column q of rows i = g, g+16, ...; 4-deep pipelined.
__global__ __launch_bounds__(256, 2) void gather_mean(
    const float* __restrict__ x, const int* __restrict__ spk,
    const int* __restrict__ ccnt, float* __restrict__ mean) {
  __shared__ float4 sacc[16][16];  // [g][q], 4 KB
  int c = blockIdx.x;
  int tid = threadIdx.x;
  int q = tid & 15, g = tid >> 4;
  int n = ccnt[c];
  const float4* x4 = (const float4*)x;  // row r at x4[r*16 + q]
  const int* sp = spk + (size_t)c * CAP;

  float ax = 0.0f, ay = 0.0f, az = 0.0f, aw = 0.0f;
  int i = g;
  for (; i + 48 < n; i += 64) {
    int p0 = sp[i];
    int p1 = sp[i + 16];
    int p2 = sp[i + 32];
    int p3 = sp[i + 48];
    float4 v0 = x4[(size_t)p0 * 16 + q];
    float4 v1 = x4[(size_t)p1 * 16 + q];
    float4 v2 = x4[(size_t)p2 * 16 + q];
    float4 v3 = x4[(size_t)p3 * 16 + q];
    ax += (v0.x + v1.x) + (v2.x + v3.x);
    ay += (v0.y + v1.y) + (v2.y + v3.y);
    az += (v0.z + v1.z) + (v2.z + v3.z);
    aw += (v0.w + v1.w) + (v2.w + v3.w);
  }
  for (; i < n; i += 16) {
    int p = sp[i];
    float4 v = x4[(size_t)p * 16 + q];
    ax += v.x; ay += v.y; az += v.z; aw += v.w;
  }
  sacc[g][q] = make_float4(ax, ay, az, aw);
  __syncthreads();

  if (tid < 64) {  // f = tid
    const float* sa = (const float*)&sacc[0][0];
    float ssum = 0.0f;
#pragma unroll
    for (int gg = 0; gg < 16; ++gg) ssum += sa[gg * 64 + tid];
    float inv = 1.0f / fmaxf((float)n, 1.0f);
    mean[(size_t)c * C_IN + tid] = ssum * inv;
  }
}

// ---- Fused KAN: mean -> h (LDS) -> out.  16 rows per block, 256 blocks ----
__global__ __launch_bounds__(256) void kan_fused(
    const float* __restrict__ mean, const float* __restrict__ bwt1,
    const float* __restrict__ swt1, const float* __restrict__ bwt2,
    const float* __restrict__ swt2, float* __restrict__ out) {
  __shared__ float s_silu[16][65];    // 4.06 KB (pad: phase-3 rr-read)
  __shared__ float s_bases[16][516];  // 32.25 KB (pad: phase-3 b128 rr-read)
  __shared__ float h_lds[16][257];    // 16.06 KB
  int row0 = blockIdx.x * 16;
  int tid = threadIdx.x;

  // ---- phase 1: stage silu + spline bases of the 16 mean rows ----
  for (int p = tid; p < 16 * 64; p += 256) {
    int r = p >> 6, i = p & 63;
    float xv = mean[(row0 + r) * C_IN + i];
    s_silu[r][i] = silu_f(xv);
    float b[8];
    bspline8(xv, b);
    float4* dst = (float4*)&s_bases[r][i * 8];
    dst[0] = make_float4(b[0], b[1], b[2], b[3]);
    dst[1] = make_float4(b[4], b[5], b[6], b[7]);
  }
  __syncthreads();

  // ---- phase 2: KAN layer 1, h into LDS; o = tid ----
  {
    int o = tid;
    float acc[16];
#pragma unroll
    for (int r = 0; r < 16; ++r) acc[r] = 0.0f;
    for (int i = 0; i < C_IN; ++i) {
      float wb = bwt1[i * H1_N + o];
      const float4* wp = (const float4*)&swt1[(size_t)(i * H1_N + o) * 8];
      float4 w0 = wp[0], w1 = wp[1];
#pragma unroll
      for (int r = 0; r < 16; ++r) {
        float sv = s_silu[r][i];
        const float4* bp = (const float4*)&s_bases[r][i * 8];
        float4 b0 = bp[0], b1 = bp[1];
        float a = acc[r];
        a = fmaf(sv, wb, a);
        a = fmaf(b0.x, w0.x, a); a = fmaf(b0.y, w0.y, a);
        a = fmaf(b0.z, w0.z, a); a = fmaf(b0.w, w0.w, a);
        a = fmaf(b1.x, w1.x, a); a = fmaf(b1.y, w1.y, a);
        a = fmaf(b1.z, w1.z, a); a = fmaf(b1.w, w1.w, a);
        acc[r] = a;
      }
    }
    __syncthreads();  // all phase-1 reads done before h_lds fills / reuse
#pragma unroll
    for (int r = 0; r < 16; ++r) h_lds[r][o] = acc[r];
  }
  __syncthreads();

  // ---- phase 3: KAN layer 2 from h_lds; (o2, rr) = (tid&15, tid>>4) ----
  int o2 = tid & 15, rr = tid >> 4;
  float acc2 = 0.0f;
  for (int ic0 = 0; ic0 < H1_N; ic0 += 64) {
    for (int p = tid; p < 16 * 64; p += 256) {
      int r = p >> 6, i = p & 63;
      float xv = h_lds[r][ic0 + i];
      s_silu[r][i] = silu_f(xv);
      float b[8];
      bspline8(xv, b);
      float4* dst = (float4*)&s_bases[r][i * 8];
      dst[0] = make_float4(b[0], b[1], b[2], b[3]);
      dst[1] = make_float4(b[4], b[5], b[6], b[7]);
    }
    __syncthreads();

    for (int i = 0; i < 64; ++i) {
      int gi = ic0 + i;
      float wb = bwt2[gi * NCLS_N + o2];
      const float4* wp = (const float4*)&swt2[(gi * NCLS_N + o2) * 8];
      float4 w0 = wp[0], w1 = wp[1];
      float sv = s_silu[rr][i];
      const float4* bp = (const float4*)&s_bases[rr][i * 8];
      float4 b0 = bp[0], b1 = bp[1];
      float sp = b0.x * w0.x + b0.y * w0.y + b0.z * w0.z + b0.w * w0.w
               + b1.x * w1.x + b1.y * w1.y + b1.z * w1.z + b1.w * w1.w;
      acc2 = fmaf(sv, wb, acc2);
      acc2 += sp;
    }
    __syncthreads();
  }
  out[(row0 + rr) * NCLS_N + o2] = acc2;
}

extern "C" void kernel_launch(void* const* d_in, const int* in_sizes, int n_in,
                              void* d_out, int out_size, void* d_ws, size_t ws_size,
                              hipStream_t stream) {
  const float* x   = (const float*)d_in[0];
  const int*   cls = (const int*)d_in[1];
  const float* bw1 = (const float*)d_in[2];
  const float* sw1 = (const float*)d_in[3];
  const float* sc1 = (const float*)d_in[4];
  const float* bw2 = (const float*)d_in[5];
  const float* sw2 = (const float*)d_in[6];
  const float* sc2 = (const float*)d_in[7];
  float* out = (float*)d_out;

  float* mean = (float*)d_ws;                   // 4096*64 f    (1 MB)
  int*   ccnt = (int*)(mean + K_CLS * C_IN);    // 4096         (16 KB)
  int*   spk  = ccnt + K_CLS;                   // 4096*512     (8 MB)
  float* swt1 = (float*)(spk + K_CLS * CAP);    // 64*256*8     (512 KB)
  float* bwt1 = swt1 + C_IN * H1_N * 8;         // 64*256
  float* swt2 = bwt1 + C_IN * H1_N;             // 256*16*8     (128 KB)
  float* bwt2 = swt2 + H1_N * NCLS_N * 8;       // 256*16

  hipMemsetAsync(ccnt, 0, K_CLS * sizeof(int), stream);
  transpose_w<<<C_IN + H1_N / 2, 256, 0, stream>>>(
      bw1, sw1, sc1, bw2, sw2, sc2, bwt1, swt1, bwt2, swt2);
  scatter_atomic<<<SCAT_BLOCKS, 1024, 0, stream>>>(cls, ccnt, spk);
  gather_mean<<<K_CLS, 256, 0, stream>>>(x, spk, ccnt, mean);
  kan_fused<<<K_CLS / 16, 256, 0, stream>>>(mean, bwt1, swt1, bwt2, swt2, out);
}

// Round 9
// 166.222 us; speedup vs baseline: 1.1770x; 1.1770x over previous
//
#include <hip/hip_runtime.h>

#define HW_N 1048576
#define C_IN 64
#define K_CLS 4096
#define H1_N 256
#define NCLS_N 16
#define SCAT_BLOCKS 256
#define ROWS_PER_SCAT (HW_N / SCAT_BLOCKS)  // 4096
#define CAP 512                              // slots per cluster (max n ~ 336)

__device__ __forceinline__ float silu_f(float x) {
  return x / (1.0f + expf(-x));
}

// Degree-3 B-spline bases on the uniform grid g[j] = 0.4*(j-3) - 1, j=0..11.
__device__ __forceinline__ void bspline8(float x, float* b) {
  float t[11];
#pragma unroll
  for (int j = 0; j < 11; ++j) {
    float g0 = 0.4f * (float)(j - 3) - 1.0f;
    float g1 = 0.4f * (float)(j - 2) - 1.0f;
    t[j] = (x >= g0 && x < g1) ? 1.0f : 0.0f;
  }
#pragma unroll
  for (int k = 1; k <= 3; ++k) {
#pragma unroll 10
    for (int j = 0; j + k < 11; ++j) {
      float gj   = 0.4f * (float)(j - 3) - 1.0f;
      float gj1  = 0.4f * (float)(j - 2) - 1.0f;
      float gjk  = 0.4f * (float)(j + k - 3) - 1.0f;
      float gjk1 = 0.4f * (float)(j + k - 2) - 1.0f;
      float left  = (x - gj) / (gjk - gj);
      float right = (gjk1 - x) / (gjk1 - gj1);
      t[j] = left * t[j] + right * t[j + 1];
    }
  }
#pragma unroll
  for (int g = 0; g < 8; ++g) b[g] = t[g];
}

// ---- Fused weight transposes (pre-scaled by spline_scaler) ----
__global__ __launch_bounds__(256) void transpose_w(
    const float* __restrict__ bw1, const float* __restrict__ sw1,
    const float* __restrict__ sc1, const float* __restrict__ bw2,
    const float* __restrict__ sw2, const float* __restrict__ sc2,
    float* __restrict__ bwt1, float* __restrict__ swt1,
    float* __restrict__ bwt2, float* __restrict__ swt2) {
  int bid = blockIdx.x, tid = threadIdx.x;
  if (bid < C_IN) {
    int i = bid, o = tid;
    float sc = sc1[o * C_IN + i];
    bwt1[i * H1_N + o] = bw1[o * C_IN + i];
    const float4* src = (const float4*)&sw1[(size_t)(o * C_IN + i) * 8];
    float4 a = src[0], b = src[1];
    a.x *= sc; a.y *= sc; a.z *= sc; a.w *= sc;
    b.x *= sc; b.y *= sc; b.z *= sc; b.w *= sc;
    float4* dst = (float4*)&swt1[(size_t)(i * H1_N + o) * 8];
    dst[0] = a; dst[1] = b;
  } else {
    int gi = (bid - C_IN) * 2 + (tid >> 7);
    int t = tid & 127;
    int o = t >> 3, e = t & 7;
    swt2[(gi * NCLS_N + o) * 8 + e] =
        sw2[(size_t)(o * H1_N + gi) * 8 + e] * sc2[o * H1_N + gi];
    if (t < NCLS_N) bwt2[gi * NCLS_N + t] = bw2[t * H1_N + gi];
  }
}

// ---- Scatter: block-aggregated atomic slot reservation (full machine) ----
__global__ __launch_bounds__(1024) void scatter_atomic(
    const int* __restrict__ cls, int* __restrict__ ccnt,
    int* __restrict__ spk) {
  __shared__ int lhist[K_CLS];  // 16 KB
  int b = blockIdx.x, tid = threadIdx.x;
  for (int c = tid; c < K_CLS; c += 1024) lhist[c] = 0;
  __syncthreads();
  int r0 = b * ROWS_PER_SCAT;
  for (int r = r0 + tid; r < r0 + ROWS_PER_SCAT; r += 1024)
    atomicAdd(&lhist[cls[r]], 1);
  __syncthreads();
  for (int c = tid; c < K_CLS; c += 1024) {
    int n = lhist[c];
    lhist[c] = n ? atomicAdd(&ccnt[c], n) : 0;
  }
  __syncthreads();
  for (int r = r0 + tid; r < r0 + ROWS_PER_SCAT; r += 1024) {
    int c = cls[r];
    int pos = atomicAdd(&lhist[c], 1);
    spk[(size_t)c * CAP + pos] = r;
  }
}

// ---- Gather rows, register-accumulate -> mean ----
// One block per cluster; (g,q) = (tid>>4, tid&15); 4-deep pipelined.
// launch_bounds(256,4): <=64 VGPR -> 4 blocks/CU -> 64 KB loads in flight/CU.
__global__ __launch_bounds__(256, 4) void gather_mean(
    const float* __restrict__ x, const int* __restrict__ spk,
    const int* __restrict__ ccnt, float* __restrict__ mean) {
  __shared__ float4 sacc[16][16];  // [g][q], 4 KB
  int c = blockIdx.x;
  int tid = threadIdx.x;
  int q = tid & 15, g = tid >> 4;
  int n = ccnt[c];
  const float4* x4 = (const float4*)x;  // row r at x4[r*16 + q]
  const int* sp = spk + (size_t)c * CAP;

  float ax = 0.0f, ay = 0.0f, az = 0.0f, aw = 0.0f;
  int i = g;
  for (; i + 48 < n; i += 64) {
    int p0 = sp[i];
    int p1 = sp[i + 16];
    int p2 = sp[i + 32];
    int p3 = sp[i + 48];
    float4 v0 = x4[(size_t)p0 * 16 + q];
    float4 v1 = x4[(size_t)p1 * 16 + q];
    float4 v2 = x4[(size_t)p2 * 16 + q];
    float4 v3 = x4[(size_t)p3 * 16 + q];
    ax += (v0.x + v1.x) + (v2.x + v3.x);
    ay += (v0.y + v1.y) + (v2.y + v3.y);
    az += (v0.z + v1.z) + (v2.z + v3.z);
    aw += (v0.w + v1.w) + (v2.w + v3.w);
  }
  for (; i < n; i += 16) {
    int p = sp[i];
    float4 v = x4[(size_t)p * 16 + q];
    ax += v.x; ay += v.y; az += v.z; aw += v.w;
  }
  sacc[g][q] = make_float4(ax, ay, az, aw);
  __syncthreads();

  if (tid < 64) {  // f = tid
    const float* sa = (const float*)&sacc[0][0];
    float ssum = 0.0f;
#pragma unroll
    for (int gg = 0; gg < 16; ++gg) ssum += sa[gg * 64 + tid];
    float inv = 1.0f / fmaxf((float)n, 1.0f);
    mean[(size_t)c * C_IN + tid] = ssum * inv;
  }
}

// ---------------- KAN layer 1 (64 -> 256), transposed weights ----------------
__global__ __launch_bounds__(256) void kan1(
    const float* __restrict__ mean, const float* __restrict__ bwt1,
    const float* __restrict__ swt1, float* __restrict__ h) {
  __shared__ float s_silu[8][64];      // 2 KB
  __shared__ float s_bases[8][64][8];  // 16 KB
  int row0 = blockIdx.x * 8;
  int tid = threadIdx.x;

  for (int p = tid; p < 8 * 64; p += 256) {
    int r = p >> 6, i = p & 63;
    float xv = mean[(row0 + r) * C_IN + i];
    s_silu[r][i] = silu_f(xv);
    float b[8];
    bspline8(xv, b);
    float4* dst = (float4*)&s_bases[r][i][0];
    dst[0] = make_float4(b[0], b[1], b[2], b[3]);
    dst[1] = make_float4(b[4], b[5], b[6], b[7]);
  }
  __syncthreads();

  int o = tid;
  float acc[8];
#pragma unroll
  for (int r = 0; r < 8; ++r) acc[r] = 0.0f;

  for (int i = 0; i < C_IN; ++i) {
    float wb = bwt1[i * H1_N + o];                          // coalesced
    const float4* wp = (const float4*)&swt1[(size_t)(i * H1_N + o) * 8];
    float4 w0 = wp[0], w1 = wp[1];                          // pre-scaled
#pragma unroll
    for (int r = 0; r < 8; ++r) {
      float sv = s_silu[r][i];
      const float4* bp = (const float4*)&s_bases[r][i][0];
      float4 b0 = bp[0], b1 = bp[1];
      float a = acc[r];
      a = fmaf(sv, wb, a);
      a = fmaf(b0.x, w0.x, a); a = fmaf(b0.y, w0.y, a);
      a = fmaf(b0.z, w0.z, a); a = fmaf(b0.w, w0.w, a);
      a = fmaf(b1.x, w1.x, a); a = fmaf(b1.y, w1.y, a);
      a = fmaf(b1.z, w1.z, a); a = fmaf(b1.w, w1.w, a);
      acc[r] = a;
    }
  }
#pragma unroll
  for (int r = 0; r < 8; ++r) h[(row0 + r) * H1_N + o] = acc[r];
}

// ---------------- KAN layer 2 (256 -> 16), transposed weights ----------------
__global__ __launch_bounds__(256) void kan2(
    const float* __restrict__ h, const float* __restrict__ bwt2,
    const float* __restrict__ swt2, float* __restrict__ out) {
  __shared__ float s_silu[16][65];
  __shared__ float s_bases[16][516];
  int row0 = blockIdx.x * 16;
  int tid = threadIdx.x;
  int o = tid & 15, rr = tid >> 4;
  float acc = 0.0f;

  for (int ic0 = 0; ic0 < H1_N; ic0 += 64) {
    for (int p = tid; p < 16 * 64; p += 256) {
      int r = p >> 6, i = p & 63;
      float xv = h[(row0 + r) * H1_N + ic0 + i];
      s_silu[r][i] = silu_f(xv);
      float b[8];
      bspline8(xv, b);
      float4* dst = (float4*)&s_bases[r][i * 8];
      dst[0] = make_float4(b[0], b[1], b[2], b[3]);
      dst[1] = make_float4(b[4], b[5], b[6], b[7]);
    }
    __syncthreads();

    for (int i = 0; i < 64; ++i) {
      int gi = ic0 + i;
      float wb = bwt2[gi * NCLS_N + o];                     // 1-line/wave
      const float4* wp = (const float4*)&swt2[(gi * NCLS_N + o) * 8];
      float4 w0 = wp[0], w1 = wp[1];                        // pre-scaled
      float sv = s_silu[rr][i];
      const float4* bp = (const float4*)&s_bases[rr][i * 8];
      float4 b0 = bp[0], b1 = bp[1];
      float sp = b0.x * w0.x + b0.y * w0.y + b0.z * w0.z + b0.w * w0.w
               + b1.x * w1.x + b1.y * w1.y + b1.z * w1.z + b1.w * w1.w;
      acc = fmaf(sv, wb, acc);
      acc += sp;
    }
    __syncthreads();
  }
  out[(row0 + rr) * NCLS_N + o] = acc;
}

extern "C" void kernel_launch(void* const* d_in, const int* in_sizes, int n_in,
                              void* d_out, int out_size, void* d_ws, size_t ws_size,
                              hipStream_t stream) {
  const float* x   = (const float*)d_in[0];
  const int*   cls = (const int*)d_in[1];
  const float* bw1 = (const float*)d_in[2];
  const float* sw1 = (const float*)d_in[3];
  const float* sc1 = (const float*)d_in[4];
  const float* bw2 = (const float*)d_in[5];
  const float* sw2 = (const float*)d_in[6];
  const float* sc2 = (const float*)d_in[7];
  float* out = (float*)d_out;

  float* mean = (float*)d_ws;                   // 4096*64 f    (1 MB)
  int*   ccnt = (int*)(mean + K_CLS * C_IN);    // 4096         (16 KB)
  int*   spk  = ccnt + K_CLS;                   // 4096*512     (8 MB)
  float* swt1 = (float*)(spk + K_CLS * CAP);    // 64*256*8     (512 KB)
  float* bwt1 = swt1 + C_IN * H1_N * 8;         // 64*256
  float* swt2 = bwt1 + C_IN * H1_N;             // 256*16*8     (128 KB)
  float* bwt2 = swt2 + H1_N * NCLS_N * 8;       // 256*16
  float* h    = bwt2 + H1_N * NCLS_N;           // 4096*256 f   (4 MB)

  hipMemsetAsync(ccnt, 0, K_CLS * sizeof(int), stream);
  transpose_w<<<C_IN + H1_N / 2, 256, 0, stream>>>(
      bw1, sw1, sc1, bw2, sw2, sc2, bwt1, swt1, bwt2, swt2);
  scatter_atomic<<<SCAT_BLOCKS, 1024, 0, stream>>>(cls, ccnt, spk);
  gather_mean<<<K_CLS, 256, 0, stream>>>(x, spk, ccnt, mean);
  kan1<<<K_CLS / 8, 256, 0, stream>>>(mean, bwt1, swt1, h);
  kan2<<<K_CLS / 16, 256, 0, stream>>>(h, bwt2, swt2, out);
}

// Round 10
// 161.840 us; speedup vs baseline: 1.2088x; 1.0271x over previous
//
#include <hip/hip_runtime.h>

#define HW_N 1048576
#define C_IN 64
#define K_CLS 4096
#define H1_N 256
#define NCLS_N 16
#define SCAT_BLOCKS 256
#define ROWS_PER_SCAT (HW_N / SCAT_BLOCKS)  // 4096
#define CAP 512                              // slots per cluster (max n ~ 336)

__device__ __forceinline__ float silu_f(float x) {
  return x / (1.0f + expf(-x));
}

// Degree-3 B-spline bases on the uniform grid g[j] = 0.4*(j-3) - 1, j=0..11.
__device__ __forceinline__ void bspline8(float x, float* b) {
  float t[11];
#pragma unroll
  for (int j = 0; j < 11; ++j) {
    float g0 = 0.4f * (float)(j - 3) - 1.0f;
    float g1 = 0.4f * (float)(j - 2) - 1.0f;
    t[j] = (x >= g0 && x < g1) ? 1.0f : 0.0f;
  }
#pragma unroll
  for (int k = 1; k <= 3; ++k) {
#pragma unroll 10
    for (int j = 0; j + k < 11; ++j) {
      float gj   = 0.4f * (float)(j - 3) - 1.0f;
      float gj1  = 0.4f * (float)(j - 2) - 1.0f;
      float gjk  = 0.4f * (float)(j + k - 3) - 1.0f;
      float gjk1 = 0.4f * (float)(j + k - 2) - 1.0f;
      float left  = (x - gj) / (gjk - gj);
      float right = (gjk1 - x) / (gjk1 - gj1);
      t[j] = left * t[j] + right * t[j + 1];
    }
  }
#pragma unroll
  for (int g = 0; g < 8; ++g) b[g] = t[g];
}

// ---- Fused weight transposes + ccnt zeroing ----
// blocks 0..63: w1; 64..191: w2; 192..207: ccnt = 0
__global__ __launch_bounds__(256) void transpose_w(
    const float* __restrict__ bw1, const float* __restrict__ sw1,
    const float* __restrict__ sc1, const float* __restrict__ bw2,
    const float* __restrict__ sw2, const float* __restrict__ sc2,
    float* __restrict__ bwt1, float* __restrict__ swt1,
    float* __restrict__ bwt2, float* __restrict__ swt2,
    int* __restrict__ ccnt) {
  int bid = blockIdx.x, tid = threadIdx.x;
  if (bid < C_IN) {
    int i = bid, o = tid;
    float sc = sc1[o * C_IN + i];
    bwt1[i * H1_N + o] = bw1[o * C_IN + i];
    const float4* src = (const float4*)&sw1[(size_t)(o * C_IN + i) * 8];
    float4 a = src[0], b = src[1];
    a.x *= sc; a.y *= sc; a.z *= sc; a.w *= sc;
    b.x *= sc; b.y *= sc; b.z *= sc; b.w *= sc;
    float4* dst = (float4*)&swt1[(size_t)(i * H1_N + o) * 8];
    dst[0] = a; dst[1] = b;
  } else if (bid < C_IN + H1_N / 2) {
    int gi = (bid - C_IN) * 2 + (tid >> 7);
    int t = tid & 127;
    int o = t >> 3, e = t & 7;
    swt2[(gi * NCLS_N + o) * 8 + e] =
        sw2[(size_t)(o * H1_N + gi) * 8 + e] * sc2[o * H1_N + gi];
    if (t < NCLS_N) bwt2[gi * NCLS_N + t] = bw2[t * H1_N + gi];
  } else {
    ccnt[(bid - C_IN - H1_N / 2) * 256 + tid] = 0;
  }
}

// ---- Scatter: block-aggregated atomic slot reservation ----
__global__ __launch_bounds__(1024) void scatter_atomic(
    const int* __restrict__ cls, int* __restrict__ ccnt,
    int* __restrict__ spk) {
  __shared__ int lhist[K_CLS];  // 16 KB
  int b = blockIdx.x, tid = threadIdx.x;
  for (int c = tid; c < K_CLS; c += 1024) lhist[c] = 0;
  __syncthreads();
  int r0 = b * ROWS_PER_SCAT;
  for (int r = r0 + tid; r < r0 + ROWS_PER_SCAT; r += 1024)
    atomicAdd(&lhist[cls[r]], 1);
  __syncthreads();
  for (int c = tid; c < K_CLS; c += 1024) {
    int n = lhist[c];
    lhist[c] = n ? atomicAdd(&ccnt[c], n) : 0;
  }
  __syncthreads();
  for (int r = r0 + tid; r < r0 + ROWS_PER_SCAT; r += 1024) {
    int c = cls[r];
    int pos = atomicAdd(&lhist[c], 1);
    spk[(size_t)c * CAP + pos] = r;
  }
}

// ---- Gather rows, register-accumulate -> mean ----
// Indices staged in LDS (decouples idx latency from x-load vmcnt chain).
// 8-deep unmasked main loop + one predicated 8-deep epilogue (no serial tail).
__global__ __launch_bounds__(256, 4) void gather_mean(
    const float* __restrict__ x, const int* __restrict__ spk,
    const int* __restrict__ ccnt, float* __restrict__ mean) {
  __shared__ int sidx[CAP];        // 2 KB
  __shared__ float4 sacc[16][16];  // 4 KB
  int c = blockIdx.x;
  int tid = threadIdx.x;
  int q = tid & 15, g = tid >> 4;
  int n = ccnt[c];
  if (tid < CAP / 4)
    ((int4*)sidx)[tid] = ((const int4*)(spk + (size_t)c * CAP))[tid];
  __syncthreads();
  const float4* x4 = (const float4*)x;  // row r at x4[r*16 + q]

  float ax = 0.0f, ay = 0.0f, az = 0.0f, aw = 0.0f;
  int i = g;
  for (; i + 112 < n; i += 128) {
    int p0 = sidx[i];
    int p1 = sidx[i + 16];
    int p2 = sidx[i + 32];
    int p3 = sidx[i + 48];
    int p4 = sidx[i + 64];
    int p5 = sidx[i + 80];
    int p6 = sidx[i + 96];
    int p7 = sidx[i + 112];
    float4 v0 = x4[(size_t)p0 * 16 + q];
    float4 v1 = x4[(size_t)p1 * 16 + q];
    float4 v2 = x4[(size_t)p2 * 16 + q];
    float4 v3 = x4[(size_t)p3 * 16 + q];
    float4 v4 = x4[(size_t)p4 * 16 + q];
    float4 v5 = x4[(size_t)p5 * 16 + q];
    float4 v6 = x4[(size_t)p6 * 16 + q];
    float4 v7 = x4[(size_t)p7 * 16 + q];
    float tx0 = v0.x + v1.x, tx1 = v2.x + v3.x, tx2 = v4.x + v5.x, tx3 = v6.x + v7.x;
    float ty0 = v0.y + v1.y, ty1 = v2.y + v3.y, ty2 = v4.y + v5.y, ty3 = v6.y + v7.y;
    float tz0 = v0.z + v1.z, tz1 = v2.z + v3.z, tz2 = v4.z + v5.z, tz3 = v6.z + v7.z;
    float tw0 = v0.w + v1.w, tw1 = v2.w + v3.w, tw2 = v4.w + v5.w, tw3 = v6.w + v7.w;
    ax += (tx0 + tx1) + (tx2 + tx3);
    ay += (ty0 + ty1) + (ty2 + ty3);
    az += (tz0 + tz1) + (tz2 + tz3);
    aw += (tw0 + tw1) + (tw2 + tw3);
  }
  if (i < n) {  // predicated 8-deep epilogue (n>=1 here)
    int nm1 = n - 1;
    int i1 = i + 16, i2 = i + 32, i3 = i + 48;
    int i4 = i + 64, i5 = i + 80, i6 = i + 96, i7 = i + 112;
    int p0 = sidx[i];
    int p1 = sidx[i1 < nm1 ? i1 : nm1];
    int p2 = sidx[i2 < nm1 ? i2 : nm1];
    int p3 = sidx[i3 < nm1 ? i3 : nm1];
    int p4 = sidx[i4 < nm1 ? i4 : nm1];
    int p5 = sidx[i5 < nm1 ? i5 : nm1];
    int p6 = sidx[i6 < nm1 ? i6 : nm1];
    int p7 = sidx[i7 < nm1 ? i7 : nm1];
    float4 v0 = x4[(size_t)p0 * 16 + q];
    float4 v1 = x4[(size_t)p1 * 16 + q];
    float4 v2 = x4[(size_t)p2 * 16 + q];
    float4 v3 = x4[(size_t)p3 * 16 + q];
    float4 v4 = x4[(size_t)p4 * 16 + q];
    float4 v5 = x4[(size_t)p5 * 16 + q];
    float4 v6 = x4[(size_t)p6 * 16 + q];
    float4 v7 = x4[(size_t)p7 * 16 + q];
    ax += v0.x; ay += v0.y; az += v0.z; aw += v0.w;
    if (i1 < n) { ax += v1.x; ay += v1.y; az += v1.z; aw += v1.w; }
    if (i2 < n) { ax += v2.x; ay += v2.y; az += v2.z; aw += v2.w; }
    if (i3 < n) { ax += v3.x; ay += v3.y; az += v3.z; aw += v3.w; }
    if (i4 < n) { ax += v4.x; ay += v4.y; az += v4.z; aw += v4.w; }
    if (i5 < n) { ax += v5.x; ay += v5.y; az += v5.z; aw += v5.w; }
    if (i6 < n) { ax += v6.x; ay += v6.y; az += v6.z; aw += v6.w; }
    if (i7 < n) { ax += v7.x; ay += v7.y; az += v7.z; aw += v7.w; }
  }
  sacc[g][q] = make_float4(ax, ay, az, aw);
  __syncthreads();

  if (tid < 64) {  // f = tid
    const float* sa = (const float*)&sacc[0][0];
    float ssum = 0.0f;
#pragma unroll
    for (int gg = 0; gg < 16; ++gg) ssum += sa[gg * 64 + tid];
    float inv = 1.0f / fmaxf((float)n, 1.0f);
    mean[(size_t)c * C_IN + tid] = ssum * inv;
  }
}

// ---------------- KAN layer 1 (64 -> 256), transposed weights ----------------
__global__ __launch_bounds__(256) void kan1(
    const float* __restrict__ mean, const float* __restrict__ bwt1,
    const float* __restrict__ swt1, float* __restrict__ h) {
  __shared__ float s_silu[8][64];      // 2 KB
  __shared__ float s_bases[8][64][8];  // 16 KB
  int row0 = blockIdx.x * 8;
  int tid = threadIdx.x;

  for (int p = tid; p < 8 * 64; p += 256) {
    int r = p >> 6, i = p & 63;
    float xv = mean[(row0 + r) * C_IN + i];
    s_silu[r][i] = silu_f(xv);
    float b[8];
    bspline8(xv, b);
    float4* dst = (float4*)&s_bases[r][i][0];
    dst[0] = make_float4(b[0], b[1], b[2], b[3]);
    dst[1] = make_float4(b[4], b[5], b[6], b[7]);
  }
  __syncthreads();

  int o = tid;
  float acc[8];
#pragma unroll
  for (int r = 0; r < 8; ++r) acc[r] = 0.0f;

  for (int i = 0; i < C_IN; ++i) {
    float wb = bwt1[i * H1_N + o];                          // coalesced
    const float4* wp = (const float4*)&swt1[(size_t)(i * H1_N + o) * 8];
    float4 w0 = wp[0], w1 = wp[1];                          // pre-scaled
#pragma unroll
    for (int r = 0; r < 8; ++r) {
      float sv = s_silu[r][i];
      const float4* bp = (const float4*)&s_bases[r][i][0];
      float4 b0 = bp[0], b1 = bp[1];
      float a = acc[r];
      a = fmaf(sv, wb, a);
      a = fmaf(b0.x, w0.x, a); a = fmaf(b0.y, w0.y, a);
      a = fmaf(b0.z, w0.z, a); a = fmaf(b0.w, w0.w, a);
      a = fmaf(b1.x, w1.x, a); a = fmaf(b1.y, w1.y, a);
      a = fmaf(b1.z, w1.z, a); a = fmaf(b1.w, w1.w, a);
      acc[r] = a;
    }
  }
#pragma unroll
  for (int r = 0; r < 8; ++r) h[(row0 + r) * H1_N + o] = acc[r];
}

// ---------------- KAN layer 2 (256 -> 16), transposed weights ----------------
__global__ __launch_bounds__(256) void kan2(
    const float* __restrict__ h, const float* __restrict__ bwt2,
    const float* __restrict__ swt2, float* __restrict__ out) {
  __shared__ float s_silu[16][65];
  __shared__ float s_bases[16][516];
  int row0 = blockIdx.x * 16;
  int tid = threadIdx.x;
  int o = tid & 15, rr = tid >> 4;
  float acc = 0.0f;

  for (int ic0 = 0; ic0 < H1_N; ic0 += 64) {
    for (int p = tid; p < 16 * 64; p += 256) {
      int r = p >> 6, i = p & 63;
      float xv = h[(row0 + r) * H1_N + ic0 + i];
      s_silu[r][i] = silu_f(xv);
      float b[8];
      bspline8(xv, b);
      float4* dst = (float4*)&s_bases[r][i * 8];
      dst[0] = make_float4(b[0], b[1], b[2], b[3]);
      dst[1] = make_float4(b[4], b[5], b[6], b[7]);
    }
    __syncthreads();

    for (int i = 0; i < 64; ++i) {
      int gi = ic0 + i;
      float wb = bwt2[gi * NCLS_N + o];
      const float4* wp = (const float4*)&swt2[(gi * NCLS_N + o) * 8];
      float4 w0 = wp[0], w1 = wp[1];
      float sv = s_silu[rr][i];
      const float4* bp = (const float4*)&s_bases[rr][i * 8];
      float4 b0 = bp[0], b1 = bp[1];
      float sp = b0.x * w0.x + b0.y * w0.y + b0.z * w0.z + b0.w * w0.w
               + b1.x * w1.x + b1.y * w1.y + b1.z * w1.z + b1.w * w1.w;
      acc = fmaf(sv, wb, acc);
      acc += sp;
    }
    __syncthreads();
  }
  out[(row0 + rr) * NCLS_N + o] = acc;
}

extern "C" void kernel_launch(void* const* d_in, const int* in_sizes, int n_in,
                              void* d_out, int out_size, void* d_ws, size_t ws_size,
                              hipStream_t stream) {
  const float* x   = (const float*)d_in[0];
  const int*   cls = (const int*)d_in[1];
  const float* bw1 = (const float*)d_in[2];
  const float* sw1 = (const float*)d_in[3];
  const float* sc1 = (const float*)d_in[4];
  const float* bw2 = (const float*)d_in[5];
  const float* sw2 = (const float*)d_in[6];
  const float* sc2 = (const float*)d_in[7];
  float* out = (float*)d_out;

  float* mean = (float*)d_ws;                   // 4096*64 f    (1 MB)
  int*   ccnt = (int*)(mean + K_CLS * C_IN);    // 4096         (16 KB)
  int*   spk  = ccnt + K_CLS;                   // 4096*512     (8 MB)
  float* swt1 = (float*)(spk + K_CLS * CAP);    // 64*256*8     (512 KB)
  float* bwt1 = swt1 + C_IN * H1_N * 8;         // 64*256
  float* swt2 = bwt1 + C_IN * H1_N;             // 256*16*8     (128 KB)
  float* bwt2 = swt2 + H1_N * NCLS_N * 8;       // 256*16
  float* h    = bwt2 + H1_N * NCLS_N;           // 4096*256 f   (4 MB)

  transpose_w<<<C_IN + H1_N / 2 + K_CLS / 256, 256, 0, stream>>>(
      bw1, sw1, sc1, bw2, sw2, sc2, bwt1, swt1, bwt2, swt2, ccnt);
  scatter_atomic<<<SCAT_BLOCKS, 1024, 0, stream>>>(cls, ccnt, spk);
  gather_mean<<<K_CLS, 256, 0, stream>>>(x, spk, ccnt, mean);
  kan1<<<K_CLS / 8, 256, 0, stream>>>(mean, bwt1, swt1, h);
  kan2<<<K_CLS / 16, 256, 0, stream>>>(h, bwt2, swt2, out);
}

// Round 11
// 157.753 us; speedup vs baseline: 1.2402x; 1.0259x over previous
//
#include <hip/hip_runtime.h>

#define HW_N 1048576
#define C_IN 64
#define K_CLS 4096
#define H1_N 256
#define NCLS_N 16
#define SCAT_BLOCKS 256
#define ROWS_PER_SCAT (HW_N / SCAT_BLOCKS)  // 4096
#define CAP 512                              // slots per cluster (max n ~ 336)
#define CLPB 16                              // clusters per mega block

__device__ __forceinline__ float silu_f(float x) {
  return x / (1.0f + expf(-x));
}

// Degree-3 B-spline bases on the uniform grid g[j] = 0.4*(j-3) - 1, j=0..11.
__device__ __forceinline__ void bspline8(float x, float* b) {
  float t[11];
#pragma unroll
  for (int j = 0; j < 11; ++j) {
    float g0 = 0.4f * (float)(j - 3) - 1.0f;
    float g1 = 0.4f * (float)(j - 2) - 1.0f;
    t[j] = (x >= g0 && x < g1) ? 1.0f : 0.0f;
  }
#pragma unroll
  for (int k = 1; k <= 3; ++k) {
#pragma unroll 10
    for (int j = 0; j + k < 11; ++j) {
      float gj   = 0.4f * (float)(j - 3) - 1.0f;
      float gj1  = 0.4f * (float)(j - 2) - 1.0f;
      float gjk  = 0.4f * (float)(j + k - 3) - 1.0f;
      float gjk1 = 0.4f * (float)(j + k - 2) - 1.0f;
      float left  = (x - gj) / (gjk - gj);
      float right = (gjk1 - x) / (gjk1 - gj1);
      t[j] = left * t[j] + right * t[j + 1];
    }
  }
#pragma unroll
  for (int g = 0; g < 8; ++g) b[g] = t[g];
}

// ---- Fused weight transposes + ccnt zeroing ----
__global__ __launch_bounds__(256) void transpose_w(
    const float* __restrict__ bw1, const float* __restrict__ sw1,
    const float* __restrict__ sc1, const float* __restrict__ bw2,
    const float* __restrict__ sw2, const float* __restrict__ sc2,
    float* __restrict__ bwt1, float* __restrict__ swt1,
    float* __restrict__ bwt2, float* __restrict__ swt2,
    int* __restrict__ ccnt) {
  int bid = blockIdx.x, tid = threadIdx.x;
  if (bid < C_IN) {
    int i = bid, o = tid;
    float sc = sc1[o * C_IN + i];
    bwt1[i * H1_N + o] = bw1[o * C_IN + i];
    const float4* src = (const float4*)&sw1[(size_t)(o * C_IN + i) * 8];
    float4 a = src[0], b = src[1];
    a.x *= sc; a.y *= sc; a.z *= sc; a.w *= sc;
    b.x *= sc; b.y *= sc; b.z *= sc; b.w *= sc;
    float4* dst = (float4*)&swt1[(size_t)(i * H1_N + o) * 8];
    dst[0] = a; dst[1] = b;
  } else if (bid < C_IN + H1_N / 2) {
    int gi = (bid - C_IN) * 2 + (tid >> 7);
    int t = tid & 127;
    int o = t >> 3, e = t & 7;
    swt2[(gi * NCLS_N + o) * 8 + e] =
        sw2[(size_t)(o * H1_N + gi) * 8 + e] * sc2[o * H1_N + gi];
    if (t < NCLS_N) bwt2[gi * NCLS_N + t] = bw2[t * H1_N + gi];
  } else {
    ccnt[(bid - C_IN - H1_N / 2) * 256 + tid] = 0;
  }
}

// ---- Scatter: block-aggregated atomic slot reservation ----
__global__ __launch_bounds__(1024) void scatter_atomic(
    const int* __restrict__ cls, int* __restrict__ ccnt,
    int* __restrict__ spk) {
  __shared__ int lhist[K_CLS];  // 16 KB
  int b = blockIdx.x, tid = threadIdx.x;
  for (int c = tid; c < K_CLS; c += 1024) lhist[c] = 0;
  __syncthreads();
  int r0 = b * ROWS_PER_SCAT;
  for (int r = r0 + tid; r < r0 + ROWS_PER_SCAT; r += 1024)
    atomicAdd(&lhist[cls[r]], 1);
  __syncthreads();
  for (int c = tid; c < K_CLS; c += 1024) {
    int n = lhist[c];
    lhist[c] = n ? atomicAdd(&ccnt[c], n) : 0;
  }
  __syncthreads();
  for (int r = r0 + tid; r < r0 + ROWS_PER_SCAT; r += 1024) {
    int c = cls[r];
    int pos = atomicAdd(&lhist[c], 1);
    spk[(size_t)c * CAP + pos] = r;
  }
}

// ---- Mega: gather means (16 clusters) -> kan1 -> kan2, all in LDS ----
// LDS overlap: sidx (32 KB, gather phase) aliases s_bases (33 KB, kan phase).
// Peak 57.9 KB -> 2 blocks/CU: one block's kan-VALU overlaps the other's
// gather-memory.
#define SM_BASES 0
#define SM_MEAN  33024
#define SM_SILU  (33024 + 4160)
#define SM_H     (33024 + 8320)
#define SM_SN    (33024 + 8320 + 16448)
#define SM_TOTAL (SM_SN + 64)

__global__ __launch_bounds__(256, 2) void mega(
    const float* __restrict__ x, const int* __restrict__ spk,
    const int* __restrict__ ccnt, const float* __restrict__ bwt1,
    const float* __restrict__ swt1, const float* __restrict__ bwt2,
    const float* __restrict__ swt2, float* __restrict__ out) {
  __shared__ __align__(16) char smem[SM_TOTAL];
  int* sidx = (int*)smem;                                   // [16][512]
  float (*s_bases)[516] = (float(*)[516])smem;              // [16][516]
  float (*mean_lds)[65] = (float(*)[65])(smem + SM_MEAN);   // [16][65]
  float (*s_silu)[65]   = (float(*)[65])(smem + SM_SILU);   // [16][65]
  float (*h_lds)[257]   = (float(*)[257])(smem + SM_H);     // [16][257]
  int* sn = (int*)(smem + SM_SN);                           // [16]

  int bid = blockIdx.x, tid = threadIdx.x;

  // ---- phase 0: bulk-load this block's 16 clusters' indices + counts ----
  {
    const int4* src = (const int4*)(spk + (size_t)bid * CLPB * CAP);
    int4* dst = (int4*)sidx;
#pragma unroll
    for (int k = 0; k < CLPB * CAP / 4 / 256; ++k)
      dst[tid + k * 256] = src[tid + k * 256];
    if (tid < CLPB) sn[tid] = ccnt[bid * CLPB + tid];
  }
  __syncthreads();

  // ---- phase 1: gather. thread (cc,q) walks cluster cc's rows, col q ----
  {
    int cc = tid >> 4, q = tid & 15;
    int n = sn[cc];
    const int* sid = sidx + cc * CAP;
    const float4* x4 = (const float4*)x;
    float ax = 0.0f, ay = 0.0f, az = 0.0f, aw = 0.0f;
    int i = 0;
    for (; i + 7 < n; i += 8) {
      int p0 = sid[i],     p1 = sid[i + 1], p2 = sid[i + 2], p3 = sid[i + 3];
      int p4 = sid[i + 4], p5 = sid[i + 5], p6 = sid[i + 6], p7 = sid[i + 7];
      float4 v0 = x4[(size_t)p0 * 16 + q];
      float4 v1 = x4[(size_t)p1 * 16 + q];
      float4 v2 = x4[(size_t)p2 * 16 + q];
      float4 v3 = x4[(size_t)p3 * 16 + q];
      float4 v4 = x4[(size_t)p4 * 16 + q];
      float4 v5 = x4[(size_t)p5 * 16 + q];
      float4 v6 = x4[(size_t)p6 * 16 + q];
      float4 v7 = x4[(size_t)p7 * 16 + q];
      float tx0 = v0.x + v1.x, tx1 = v2.x + v3.x, tx2 = v4.x + v5.x, tx3 = v6.x + v7.x;
      float ty0 = v0.y + v1.y, ty1 = v2.y + v3.y, ty2 = v4.y + v5.y, ty3 = v6.y + v7.y;
      float tz0 = v0.z + v1.z, tz1 = v2.z + v3.z, tz2 = v4.z + v5.z, tz3 = v6.z + v7.z;
      float tw0 = v0.w + v1.w, tw1 = v2.w + v3.w, tw2 = v4.w + v5.w, tw3 = v6.w + v7.w;
      ax += (tx0 + tx1) + (tx2 + tx3);
      ay += (ty0 + ty1) + (ty2 + ty3);
      az += (tz0 + tz1) + (tz2 + tz3);
      aw += (tw0 + tw1) + (tw2 + tw3);
    }
    if (i < n) {  // predicated 8-deep tail
      int nm1 = n - 1;
      int i1 = i + 1, i2 = i + 2, i3 = i + 3, i4 = i + 4, i5 = i + 5,
          i6 = i + 6, i7 = i + 7;
      int p0 = sid[i];
      int p1 = sid[i1 < nm1 ? i1 : nm1];
      int p2 = sid[i2 < nm1 ? i2 : nm1];
      int p3 = sid[i3 < nm1 ? i3 : nm1];
      int p4 = sid[i4 < nm1 ? i4 : nm1];
      int p5 = sid[i5 < nm1 ? i5 : nm1];
      int p6 = sid[i6 < nm1 ? i6 : nm1];
      int p7 = sid[i7 < nm1 ? i7 : nm1];
      float4 v0 = x4[(size_t)p0 * 16 + q];
      float4 v1 = x4[(size_t)p1 * 16 + q];
      float4 v2 = x4[(size_t)p2 * 16 + q];
      float4 v3 = x4[(size_t)p3 * 16 + q];
      float4 v4 = x4[(size_t)p4 * 16 + q];
      float4 v5 = x4[(size_t)p5 * 16 + q];
      float4 v6 = x4[(size_t)p6 * 16 + q];
      float4 v7 = x4[(size_t)p7 * 16 + q];
      ax += v0.x; ay += v0.y; az += v0.z; aw += v0.w;
      if (i1 < n) { ax += v1.x; ay += v1.y; az += v1.z; aw += v1.w; }
      if (i2 < n) { ax += v2.x; ay += v2.y; az += v2.z; aw += v2.w; }
      if (i3 < n) { ax += v3.x; ay += v3.y; az += v3.z; aw += v3.w; }
      if (i4 < n) { ax += v4.x; ay += v4.y; az += v4.z; aw += v4.w; }
      if (i5 < n) { ax += v5.x; ay += v5.y; az += v5.z; aw += v5.w; }
      if (i6 < n) { ax += v6.x; ay += v6.y; az += v6.z; aw += v6.w; }
      if (i7 < n) { ax += v7.x; ay += v7.y; az += v7.z; aw += v7.w; }
    }
    float inv = 1.0f / fmaxf((float)n, 1.0f);
    mean_lds[cc][q * 4 + 0] = ax * inv;
    mean_lds[cc][q * 4 + 1] = ay * inv;
    mean_lds[cc][q * 4 + 2] = az * inv;
    mean_lds[cc][q * 4 + 3] = aw * inv;
  }
  __syncthreads();  // gather done; sidx region may now be reused as s_bases

  // ---- phase 2: stage silu + bases of the 16 mean rows ----
  for (int p = tid; p < 16 * 64; p += 256) {
    int r = p >> 6, i = p & 63;
    float xv = mean_lds[r][i];
    s_silu[r][i] = silu_f(xv);
    float b[8];
    bspline8(xv, b);
    float4* dst = (float4*)&s_bases[r][i * 8];
    dst[0] = make_float4(b[0], b[1], b[2], b[3]);
    dst[1] = make_float4(b[4], b[5], b[6], b[7]);
  }
  __syncthreads();

  // ---- phase 3: KAN layer 1, h into LDS; o = tid ----
  {
    int o = tid;
    float acc[16];
#pragma unroll
    for (int r = 0; r < 16; ++r) acc[r] = 0.0f;
    for (int i = 0; i < C_IN; ++i) {
      float wb = bwt1[i * H1_N + o];
      const float4* wp = (const float4*)&swt1[(size_t)(i * H1_N + o) * 8];
      float4 w0 = wp[0], w1 = wp[1];
#pragma unroll
      for (int r = 0; r < 16; ++r) {
        float sv = s_silu[r][i];
        const float4* bp = (const float4*)&s_bases[r][i * 8];
        float4 b0 = bp[0], b1 = bp[1];
        float a = acc[r];
        a = fmaf(sv, wb, a);
        a = fmaf(b0.x, w0.x, a); a = fmaf(b0.y, w0.y, a);
        a = fmaf(b0.z, w0.z, a); a = fmaf(b0.w, w0.w, a);
        a = fmaf(b1.x, w1.x, a); a = fmaf(b1.y, w1.y, a);
        a = fmaf(b1.z, w1.z, a); a = fmaf(b1.w, w1.w, a);
        acc[r] = a;
      }
    }
    __syncthreads();  // phase-2 buffer reads done before phase-4 restaging
#pragma unroll
    for (int r = 0; r < 16; ++r) h_lds[r][o] = acc[r];
  }
  __syncthreads();

  // ---- phase 4: KAN layer 2 from h_lds; (o2, rr) = (tid&15, tid>>4) ----
  int o2 = tid & 15, rr = tid >> 4;
  float acc2 = 0.0f;
  for (int ic0 = 0; ic0 < H1_N; ic0 += 64) {
    for (int p = tid; p < 16 * 64; p += 256) {
      int r = p >> 6, i = p & 63;
      float xv = h_lds[r][ic0 + i];
      s_silu[r][i] = silu_f(xv);
      float b[8];
      bspline8(xv, b);
      float4* dst = (float4*)&s_bases[r][i * 8];
      dst[0] = make_float4(b[0], b[1], b[2], b[3]);
      dst[1] = make_float4(b[4], b[5], b[6], b[7]);
    }
    __syncthreads();

    for (int i = 0; i < 64; ++i) {
      int gi = ic0 + i;
      float wb = bwt2[gi * NCLS_N + o2];
      const float4* wp = (const float4*)&swt2[(gi * NCLS_N + o2) * 8];
      float4 w0 = wp[0], w1 = wp[1];
      float sv = s_silu[rr][i];
      const float4* bp = (const float4*)&s_bases[rr][i * 8];
      float4 b0 = bp[0], b1 = bp[1];
      float sp = b0.x * w0.x + b0.y * w0.y + b0.z * w0.z + b0.w * w0.w
               + b1.x * w1.x + b1.y * w1.y + b1.z * w1.z + b1.w * w1.w;
      acc2 = fmaf(sv, wb, acc2);
      acc2 += sp;
    }
    __syncthreads();
  }
  out[(bid * CLPB + rr) * NCLS_N + o2] = acc2;
}

extern "C" void kernel_launch(void* const* d_in, const int* in_sizes, int n_in,
                              void* d_out, int out_size, void* d_ws, size_t ws_size,
                              hipStream_t stream) {
  const float* x   = (const float*)d_in[0];
  const int*   cls = (const int*)d_in[1];
  const float* bw1 = (const float*)d_in[2];
  const float* sw1 = (const float*)d_in[3];
  const float* sc1 = (const float*)d_in[4];
  const float* bw2 = (const float*)d_in[5];
  const float* sw2 = (const float*)d_in[6];
  const float* sc2 = (const float*)d_in[7];
  float* out = (float*)d_out;

  int*   ccnt = (int*)d_ws;                     // 4096         (16 KB)
  int*   spk  = ccnt + K_CLS;                   // 4096*512     (8 MB)
  float* swt1 = (float*)(spk + K_CLS * CAP);    // 64*256*8     (512 KB)
  float* bwt1 = swt1 + C_IN * H1_N * 8;         // 64*256
  float* swt2 = bwt1 + C_IN * H1_N;             // 256*16*8     (128 KB)
  float* bwt2 = swt2 + H1_N * NCLS_N * 8;       // 256*16

  transpose_w<<<C_IN + H1_N / 2 + K_CLS / 256, 256, 0, stream>>>(
      bw1, sw1, sc1, bw2, sw2, sc2, bwt1, swt1, bwt2, swt2, ccnt);
  scatter_atomic<<<SCAT_BLOCKS, 1024, 0, stream>>>(cls, ccnt, spk);
  mega<<<K_CLS / CLPB, 256, 0, stream>>>(
      x, spk, ccnt, bwt1, swt1, bwt2, swt2, out);
}

// Round 12
// 128.299 us; speedup vs baseline: 1.5249x; 1.2296x over previous
//
#include <hip/hip_runtime.h>

#define HW_N 1048576
#define C_IN 64
#define K_CLS 4096
#define H1_N 256
#define NCLS_N 16
#define SCAT_BLOCKS 256
#define ROWS_PER_SCAT (HW_N / SCAT_BLOCKS)  // 4096
#define CAP 512                              // slots per cluster (max n ~ 336)
#define CLPB 8                               // clusters per mega block (1/wave)

__device__ __forceinline__ float silu_f(float x) {
  return x / (1.0f + expf(-x));
}

// Degree-3 B-spline bases on the uniform grid g[j] = 0.4*(j-3) - 1, j=0..11.
__device__ __forceinline__ void bspline8(float x, float* b) {
  float t[11];
#pragma unroll
  for (int j = 0; j < 11; ++j) {
    float g0 = 0.4f * (float)(j - 3) - 1.0f;
    float g1 = 0.4f * (float)(j - 2) - 1.0f;
    t[j] = (x >= g0 && x < g1) ? 1.0f : 0.0f;
  }
#pragma unroll
  for (int k = 1; k <= 3; ++k) {
#pragma unroll 10
    for (int j = 0; j + k < 11; ++j) {
      float gj   = 0.4f * (float)(j - 3) - 1.0f;
      float gj1  = 0.4f * (float)(j - 2) - 1.0f;
      float gjk  = 0.4f * (float)(j + k - 3) - 1.0f;
      float gjk1 = 0.4f * (float)(j + k - 2) - 1.0f;
      float left  = (x - gj) / (gjk - gj);
      float right = (gjk1 - x) / (gjk1 - gj1);
      t[j] = left * t[j] + right * t[j + 1];
    }
  }
#pragma unroll
  for (int g = 0; g < 8; ++g) b[g] = t[g];
}

// ---- Fused weight transposes + ccnt zeroing ----
__global__ __launch_bounds__(256) void transpose_w(
    const float* __restrict__ bw1, const float* __restrict__ sw1,
    const float* __restrict__ sc1, const float* __restrict__ bw2,
    const float* __restrict__ sw2, const float* __restrict__ sc2,
    float* __restrict__ bwt1, float* __restrict__ swt1,
    float* __restrict__ bwt2, float* __restrict__ swt2,
    int* __restrict__ ccnt) {
  int bid = blockIdx.x, tid = threadIdx.x;
  if (bid < C_IN) {
    int i = bid, o = tid;
    float sc = sc1[o * C_IN + i];
    bwt1[i * H1_N + o] = bw1[o * C_IN + i];
    const float4* src = (const float4*)&sw1[(size_t)(o * C_IN + i) * 8];
    float4 a = src[0], b = src[1];
    a.x *= sc; a.y *= sc; a.z *= sc; a.w *= sc;
    b.x *= sc; b.y *= sc; b.z *= sc; b.w *= sc;
    float4* dst = (float4*)&swt1[(size_t)(i * H1_N + o) * 8];
    dst[0] = a; dst[1] = b;
  } else if (bid < C_IN + H1_N / 2) {
    int gi = (bid - C_IN) * 2 + (tid >> 7);
    int t = tid & 127;
    int o = t >> 3, e = t & 7;
    swt2[(gi * NCLS_N + o) * 8 + e] =
        sw2[(size_t)(o * H1_N + gi) * 8 + e] * sc2[o * H1_N + gi];
    if (t < NCLS_N) bwt2[gi * NCLS_N + t] = bw2[t * H1_N + gi];
  } else {
    ccnt[(bid - C_IN - H1_N / 2) * 256 + tid] = 0;
  }
}

// ---- Scatter: block-aggregated atomic slot reservation ----
__global__ __launch_bounds__(1024) void scatter_atomic(
    const int* __restrict__ cls, int* __restrict__ ccnt,
    int* __restrict__ spk) {
  __shared__ int lhist[K_CLS];  // 16 KB
  int b = blockIdx.x, tid = threadIdx.x;
  for (int c = tid; c < K_CLS; c += 1024) lhist[c] = 0;
  __syncthreads();
  int r0 = b * ROWS_PER_SCAT;
  for (int r = r0 + tid; r < r0 + ROWS_PER_SCAT; r += 1024)
    atomicAdd(&lhist[cls[r]], 1);
  __syncthreads();
  for (int c = tid; c < K_CLS; c += 1024) {
    int n = lhist[c];
    lhist[c] = n ? atomicAdd(&ccnt[c], n) : 0;
  }
  __syncthreads();
  for (int r = r0 + tid; r < r0 + ROWS_PER_SCAT; r += 1024) {
    int c = cls[r];
    int pos = atomicAdd(&lhist[c], 1);
    spk[(size_t)c * CAP + pos] = r;
  }
}

// ---- Mega v2: 512 thr, 8 clusters (1/wave), gather -> kan1 -> kan2 ----
// 512 blocks -> 2/CU x 8 waves = 16 waves/CU. Gather: lane (g,q) walks rows
// i===g (mod 4) 8-deep (8 iters @ n~256); shfl_xor(16,32) reduce, no barrier.
__global__ __launch_bounds__(512, 4) void mega(
    const float* __restrict__ x, const int* __restrict__ spk,
    const int* __restrict__ ccnt, const float* __restrict__ bwt1,
    const float* __restrict__ swt1, const float* __restrict__ bwt2,
    const float* __restrict__ swt2, float* __restrict__ out) {
  __shared__ float s_bases[8][516];   // 16.5 KB
  __shared__ float s_silu[8][65];     // 2 KB
  __shared__ float mean_sacc[8][65];  // 2 KB: mean (ph1-2); sacc2 (ph4)
  __shared__ float h_lds[8][257];     // 8.2 KB
  __shared__ int sn[8];

  int bid = blockIdx.x, tid = threadIdx.x;
  int wv = tid >> 6, lane = tid & 63;
  int g = lane >> 4, q = lane & 15;

  if (tid < CLPB) sn[tid] = ccnt[bid * CLPB + tid];
  __syncthreads();

  // ---- phase 1: wave wv gathers cluster bid*8+wv ----
  {
    int n = sn[wv];
    const int* sid = spk + (size_t)(bid * CLPB + wv) * CAP;
    const float4* x4 = (const float4*)x;
    float ax = 0.0f, ay = 0.0f, az = 0.0f, aw = 0.0f;
    int i = g;
    for (; i + 28 < n; i += 32) {
      int p0 = sid[i],      p1 = sid[i + 4],  p2 = sid[i + 8],  p3 = sid[i + 12];
      int p4 = sid[i + 16], p5 = sid[i + 20], p6 = sid[i + 24], p7 = sid[i + 28];
      float4 v0 = x4[(size_t)p0 * 16 + q];
      float4 v1 = x4[(size_t)p1 * 16 + q];
      float4 v2 = x4[(size_t)p2 * 16 + q];
      float4 v3 = x4[(size_t)p3 * 16 + q];
      float4 v4 = x4[(size_t)p4 * 16 + q];
      float4 v5 = x4[(size_t)p5 * 16 + q];
      float4 v6 = x4[(size_t)p6 * 16 + q];
      float4 v7 = x4[(size_t)p7 * 16 + q];
      float tx0 = v0.x + v1.x, tx1 = v2.x + v3.x, tx2 = v4.x + v5.x, tx3 = v6.x + v7.x;
      float ty0 = v0.y + v1.y, ty1 = v2.y + v3.y, ty2 = v4.y + v5.y, ty3 = v6.y + v7.y;
      float tz0 = v0.z + v1.z, tz1 = v2.z + v3.z, tz2 = v4.z + v5.z, tz3 = v6.z + v7.z;
      float tw0 = v0.w + v1.w, tw1 = v2.w + v3.w, tw2 = v4.w + v5.w, tw3 = v6.w + v7.w;
      ax += (tx0 + tx1) + (tx2 + tx3);
      ay += (ty0 + ty1) + (ty2 + ty3);
      az += (tz0 + tz1) + (tz2 + tz3);
      aw += (tw0 + tw1) + (tw2 + tw3);
    }
    if (i < n) {  // predicated 8-deep tail (remaining <= 8 per thread)
      int nm1 = n - 1;
      int i1 = i + 4, i2 = i + 8, i3 = i + 12, i4 = i + 16, i5 = i + 20,
          i6 = i + 24, i7 = i + 28;
      int p0 = sid[i];
      int p1 = sid[i1 < nm1 ? i1 : nm1];
      int p2 = sid[i2 < nm1 ? i2 : nm1];
      int p3 = sid[i3 < nm1 ? i3 : nm1];
      int p4 = sid[i4 < nm1 ? i4 : nm1];
      int p5 = sid[i5 < nm1 ? i5 : nm1];
      int p6 = sid[i6 < nm1 ? i6 : nm1];
      int p7 = sid[i7 < nm1 ? i7 : nm1];
      float4 v0 = x4[(size_t)p0 * 16 + q];
      float4 v1 = x4[(size_t)p1 * 16 + q];
      float4 v2 = x4[(size_t)p2 * 16 + q];
      float4 v3 = x4[(size_t)p3 * 16 + q];
      float4 v4 = x4[(size_t)p4 * 16 + q];
      float4 v5 = x4[(size_t)p5 * 16 + q];
      float4 v6 = x4[(size_t)p6 * 16 + q];
      float4 v7 = x4[(size_t)p7 * 16 + q];
      ax += v0.x; ay += v0.y; az += v0.z; aw += v0.w;
      if (i1 < n) { ax += v1.x; ay += v1.y; az += v1.z; aw += v1.w; }
      if (i2 < n) { ax += v2.x; ay += v2.y; az += v2.z; aw += v2.w; }
      if (i3 < n) { ax += v3.x; ay += v3.y; az += v3.z; aw += v3.w; }
      if (i4 < n) { ax += v4.x; ay += v4.y; az += v4.z; aw += v4.w; }
      if (i5 < n) { ax += v5.x; ay += v5.y; az += v5.z; aw += v5.w; }
      if (i6 < n) { ax += v6.x; ay += v6.y; az += v6.z; aw += v6.w; }
      if (i7 < n) { ax += v7.x; ay += v7.y; az += v7.z; aw += v7.w; }
    }
    // reduce the 4 g-partials within the wave
    ax += __shfl_xor(ax, 16); ax += __shfl_xor(ax, 32);
    ay += __shfl_xor(ay, 16); ay += __shfl_xor(ay, 32);
    az += __shfl_xor(az, 16); az += __shfl_xor(az, 32);
    aw += __shfl_xor(aw, 16); aw += __shfl_xor(aw, 32);
    if (g == 0) {
      float inv = 1.0f / fmaxf((float)n, 1.0f);
      mean_sacc[wv][q * 4 + 0] = ax * inv;
      mean_sacc[wv][q * 4 + 1] = ay * inv;
      mean_sacc[wv][q * 4 + 2] = az * inv;
      mean_sacc[wv][q * 4 + 3] = aw * inv;
    }
  }
  __syncthreads();

  // ---- phase 2: stage silu + bases of 8 mean rows (1 item/thread) ----
  {
    int r = tid >> 6, i = tid & 63;
    float xv = mean_sacc[r][i];
    s_silu[r][i] = silu_f(xv);
    float b[8];
    bspline8(xv, b);
    float4* dst = (float4*)&s_bases[r][i * 8];
    dst[0] = make_float4(b[0], b[1], b[2], b[3]);
    dst[1] = make_float4(b[4], b[5], b[6], b[7]);
  }
  __syncthreads();

  // ---- phase 3: kan1; (o, ih) = (tid&255, tid>>8); i in [ih*32, ih*32+32) ----
  {
    int o = tid & 255, ih = tid >> 8;
    float acc[8];
#pragma unroll
    for (int r = 0; r < 8; ++r) acc[r] = 0.0f;
    int i0 = ih * 32;
    for (int i = i0; i < i0 + 32; ++i) {
      float wb = bwt1[i * H1_N + o];
      const float4* wp = (const float4*)&swt1[(size_t)(i * H1_N + o) * 8];
      float4 w0 = wp[0], w1 = wp[1];
#pragma unroll
      for (int r = 0; r < 8; ++r) {
        float sv = s_silu[r][i];
        const float4* bp = (const float4*)&s_bases[r][i * 8];
        float4 b0 = bp[0], b1 = bp[1];
        float a = acc[r];
        a = fmaf(sv, wb, a);
        a = fmaf(b0.x, w0.x, a); a = fmaf(b0.y, w0.y, a);
        a = fmaf(b0.z, w0.z, a); a = fmaf(b0.w, w0.w, a);
        a = fmaf(b1.x, w1.x, a); a = fmaf(b1.y, w1.y, a);
        a = fmaf(b1.z, w1.z, a); a = fmaf(b1.w, w1.w, a);
        acc[r] = a;
      }
    }
    if (ih == 0) {
#pragma unroll
      for (int r = 0; r < 8; ++r) h_lds[r][o] = acc[r];
    }
    __syncthreads();
    if (ih == 1) {
#pragma unroll
      for (int r = 0; r < 8; ++r) h_lds[r][o] += acc[r];
    }
  }
  __syncthreads();

  // ---- phase 4: kan2; (o2, rr, jh) = (tid&15, (tid>>4)&7, tid>>7) ----
  {
    int o2 = tid & 15, rr = (tid >> 4) & 7, jh = tid >> 7;  // jh in 0..3
    float acc2 = 0.0f;
    for (int ic0 = 0; ic0 < H1_N; ic0 += 64) {
      {  // stage chunk (1 item/thread)
        int r = tid >> 6, i = tid & 63;
        float xv = h_lds[r][ic0 + i];
        s_silu[r][i] = silu_f(xv);
        float b[8];
        bspline8(xv, b);
        float4* dst = (float4*)&s_bases[r][i * 8];
        dst[0] = make_float4(b[0], b[1], b[2], b[3]);
        dst[1] = make_float4(b[4], b[5], b[6], b[7]);
      }
      __syncthreads();
      int ib = jh * 16;
      for (int i = ib; i < ib + 16; ++i) {
        int gi = ic0 + i;
        float wb = bwt2[gi * NCLS_N + o2];
        const float4* wp = (const float4*)&swt2[(gi * NCLS_N + o2) * 8];
        float4 w0 = wp[0], w1 = wp[1];
        float sv = s_silu[rr][i];
        const float4* bp = (const float4*)&s_bases[rr][i * 8];
        float4 b0 = bp[0], b1 = bp[1];
        float sp = b0.x * w0.x + b0.y * w0.y + b0.z * w0.z + b0.w * w0.w
                 + b1.x * w1.x + b1.y * w1.y + b1.z * w1.z + b1.w * w1.w;
        acc2 = fmaf(sv, wb, acc2);
        acc2 += sp;
      }
      __syncthreads();
    }
    // reduce 4 jh-partials via the (dead) mean buffer
    float* sac = &mean_sacc[0][0];  // 520 floats >= 512
    sac[jh * 128 + rr * 16 + o2] = acc2;
    __syncthreads();
    if (tid < 128) {
      float s = sac[tid] + sac[128 + tid] + sac[256 + tid] + sac[384 + tid];
      out[(bid * CLPB + (tid >> 4)) * NCLS_N + (tid & 15)] = s;
    }
  }
}

extern "C" void kernel_launch(void* const* d_in, const int* in_sizes, int n_in,
                              void* d_out, int out_size, void* d_ws, size_t ws_size,
                              hipStream_t stream) {
  const float* x   = (const float*)d_in[0];
  const int*   cls = (const int*)d_in[1];
  const float* bw1 = (const float*)d_in[2];
  const float* sw1 = (const float*)d_in[3];
  const float* sc1 = (const float*)d_in[4];
  const float* bw2 = (const float*)d_in[5];
  const float* sw2 = (const float*)d_in[6];
  const float* sc2 = (const float*)d_in[7];
  float* out = (float*)d_out;

  int*   ccnt = (int*)d_ws;                     // 4096         (16 KB)
  int*   spk  = ccnt + K_CLS;                   // 4096*512     (8 MB)
  float* swt1 = (float*)(spk + K_CLS * CAP);    // 64*256*8     (512 KB)
  float* bwt1 = swt1 + C_IN * H1_N * 8;         // 64*256
  float* swt2 = bwt1 + C_IN * H1_N;             // 256*16*8     (128 KB)
  float* bwt2 = swt2 + H1_N * NCLS_N * 8;       // 256*16

  transpose_w<<<C_IN + H1_N / 2 + K_CLS / 256, 256, 0, stream>>>(
      bw1, sw1, sc1, bw2, sw2, sc2, bwt1, swt1, bwt2, swt2, ccnt);
  scatter_atomic<<<SCAT_BLOCKS, 1024, 0, stream>>>(cls, ccnt, spk);
  mega<<<K_CLS / CLPB, 512, 0, stream>>>(
      x, spk, ccnt, bwt1, swt1, bwt2, swt2, out);
}

// Round 13
// 127.387 us; speedup vs baseline: 1.5358x; 1.0072x over previous
//
#include <hip/hip_runtime.h>

#define HW_N 1048576
#define C_IN 64
#define K_CLS 4096
#define H1_N 256
#define NCLS_N 16
#define SCAT_BLOCKS 256
#define ROWS_PER_SCAT (HW_N / SCAT_BLOCKS)  // 4096
#define CAP 512                              // slots per cluster (max n ~ 336)
#define CLPB 8                               // clusters per mega block (1/wave)

__device__ __forceinline__ float silu_f(float x) {
  return x / (1.0f + expf(-x));
}

// Degree-3 B-spline bases on the uniform grid g[j] = 0.4*(j-3) - 1, j=0..11.
__device__ __forceinline__ void bspline8(float x, float* b) {
  float t[11];
#pragma unroll
  for (int j = 0; j < 11; ++j) {
    float g0 = 0.4f * (float)(j - 3) - 1.0f;
    float g1 = 0.4f * (float)(j - 2) - 1.0f;
    t[j] = (x >= g0 && x < g1) ? 1.0f : 0.0f;
  }
#pragma unroll
  for (int k = 1; k <= 3; ++k) {
#pragma unroll 10
    for (int j = 0; j + k < 11; ++j) {
      float gj   = 0.4f * (float)(j - 3) - 1.0f;
      float gj1  = 0.4f * (float)(j - 2) - 1.0f;
      float gjk  = 0.4f * (float)(j + k - 3) - 1.0f;
      float gjk1 = 0.4f * (float)(j + k - 2) - 1.0f;
      float left  = (x - gj) / (gjk - gj);
      float right = (gjk1 - x) / (gjk1 - gj1);
      t[j] = left * t[j] + right * t[j + 1];
    }
  }
#pragma unroll
  for (int g = 0; g < 8; ++g) b[g] = t[g];
}

// ---- Fused weight transposes + ccnt zeroing ----
__global__ __launch_bounds__(256) void transpose_w(
    const float* __restrict__ bw1, const float* __restrict__ sw1,
    const float* __restrict__ sc1, const float* __restrict__ bw2,
    const float* __restrict__ sw2, const float* __restrict__ sc2,
    float* __restrict__ bwt1, float* __restrict__ swt1,
    float* __restrict__ bwt2, float* __restrict__ swt2,
    int* __restrict__ ccnt) {
  int bid = blockIdx.x, tid = threadIdx.x;
  if (bid < C_IN) {
    int i = bid, o = tid;
    float sc = sc1[o * C_IN + i];
    bwt1[i * H1_N + o] = bw1[o * C_IN + i];
    const float4* src = (const float4*)&sw1[(size_t)(o * C_IN + i) * 8];
    float4 a = src[0], b = src[1];
    a.x *= sc; a.y *= sc; a.z *= sc; a.w *= sc;
    b.x *= sc; b.y *= sc; b.z *= sc; b.w *= sc;
    float4* dst = (float4*)&swt1[(size_t)(i * H1_N + o) * 8];
    dst[0] = a; dst[1] = b;
  } else if (bid < C_IN + H1_N / 2) {
    int gi = (bid - C_IN) * 2 + (tid >> 7);
    int t = tid & 127;
    int o = t >> 3, e = t & 7;
    swt2[(gi * NCLS_N + o) * 8 + e] =
        sw2[(size_t)(o * H1_N + gi) * 8 + e] * sc2[o * H1_N + gi];
    if (t < NCLS_N) bwt2[gi * NCLS_N + t] = bw2[t * H1_N + gi];
  } else {
    ccnt[(bid - C_IN - H1_N / 2) * 256 + tid] = 0;
  }
}

// ---- Scatter: block-aggregated atomic slot reservation ----
__global__ __launch_bounds__(1024) void scatter_atomic(
    const int* __restrict__ cls, int* __restrict__ ccnt,
    int* __restrict__ spk) {
  __shared__ int lhist[K_CLS];  // 16 KB
  int b = blockIdx.x, tid = threadIdx.x;
  for (int c = tid; c < K_CLS; c += 1024) lhist[c] = 0;
  __syncthreads();
  int r0 = b * ROWS_PER_SCAT;
  for (int r = r0 + tid; r < r0 + ROWS_PER_SCAT; r += 1024)
    atomicAdd(&lhist[cls[r]], 1);
  __syncthreads();
  for (int c = tid; c < K_CLS; c += 1024) {
    int n = lhist[c];
    lhist[c] = n ? atomicAdd(&ccnt[c], n) : 0;
  }
  __syncthreads();
  for (int r = r0 + tid; r < r0 + ROWS_PER_SCAT; r += 1024) {
    int c = cls[r];
    int pos = atomicAdd(&lhist[c], 1);
    spk[(size_t)c * CAP + pos] = r;
  }
}

// ---- Mega v3: idx-prefetch pipelined gather -> kan1 -> kan2 ----
// 512 blocks x 512 thr (wave = cluster). Gather: next batch's indices are
// prefetched while current batch's x-loads are in flight (sid safe to CAP).
__global__ __launch_bounds__(512, 4) void mega(
    const float* __restrict__ x, const int* __restrict__ spk,
    const int* __restrict__ ccnt, const float* __restrict__ bwt1,
    const float* __restrict__ swt1, const float* __restrict__ bwt2,
    const float* __restrict__ swt2, float* __restrict__ out) {
  __shared__ float s_bases[8][516];   // 16.5 KB
  __shared__ float s_silu[8][65];     // 2 KB
  __shared__ float mean_sacc[8][65];  // 2 KB: mean (ph1-2); sacc2 (ph4)
  __shared__ float h_lds[8][257];     // 8.2 KB

  int bid = blockIdx.x, tid = threadIdx.x;
  int wv = tid >> 6, lane = tid & 63;
  int g = lane >> 4, q = lane & 15;

  // ---- phase 1: wave wv gathers cluster bid*8+wv (idx-prefetch pipeline) ----
  {
    int cidx = bid * CLPB + wv;
    int n = ccnt[cidx];  // wave-uniform -> scalar load, no barrier needed
    const int* sid = spk + (size_t)cidx * CAP;
    const float4* x4 = (const float4*)x;
    float ax = 0.0f, ay = 0.0f, az = 0.0f, aw = 0.0f;
    int i = g;
    if (i + 28 < n) {
      int pa0 = sid[i],      pa1 = sid[i + 4],  pa2 = sid[i + 8],  pa3 = sid[i + 12];
      int pa4 = sid[i + 16], pa5 = sid[i + 20], pa6 = sid[i + 24], pa7 = sid[i + 28];
      while (true) {
        // issue current batch's x-loads
        float4 v0 = x4[(size_t)pa0 * 16 + q];
        float4 v1 = x4[(size_t)pa1 * 16 + q];
        float4 v2 = x4[(size_t)pa2 * 16 + q];
        float4 v3 = x4[(size_t)pa3 * 16 + q];
        float4 v4 = x4[(size_t)pa4 * 16 + q];
        float4 v5 = x4[(size_t)pa5 * 16 + q];
        float4 v6 = x4[(size_t)pa6 * 16 + q];
        float4 v7 = x4[(size_t)pa7 * 16 + q];
        // prefetch next batch's indices (always in-bounds: < CAP)
        int ib = i + 32;
        int pb0 = sid[ib],      pb1 = sid[ib + 4],  pb2 = sid[ib + 8],  pb3 = sid[ib + 12];
        int pb4 = sid[ib + 16], pb5 = sid[ib + 20], pb6 = sid[ib + 24], pb7 = sid[ib + 28];
        // consume current batch
        float tx0 = v0.x + v1.x, tx1 = v2.x + v3.x, tx2 = v4.x + v5.x, tx3 = v6.x + v7.x;
        float ty0 = v0.y + v1.y, ty1 = v2.y + v3.y, ty2 = v4.y + v5.y, ty3 = v6.y + v7.y;
        float tz0 = v0.z + v1.z, tz1 = v2.z + v3.z, tz2 = v4.z + v5.z, tz3 = v6.z + v7.z;
        float tw0 = v0.w + v1.w, tw1 = v2.w + v3.w, tw2 = v4.w + v5.w, tw3 = v6.w + v7.w;
        ax += (tx0 + tx1) + (tx2 + tx3);
        ay += (ty0 + ty1) + (ty2 + ty3);
        az += (tz0 + tz1) + (tz2 + tz3);
        aw += (tw0 + tw1) + (tw2 + tw3);
        i = ib;
        pa0 = pb0; pa1 = pb1; pa2 = pb2; pa3 = pb3;
        pa4 = pb4; pa5 = pb5; pa6 = pb6; pa7 = pb7;
        if (!(i + 28 < n)) break;
      }
    }
    if (i < n) {  // predicated 8-deep tail (remaining <= 8 rows per thread)
      int nm1 = n - 1;
      int i1 = i + 4, i2 = i + 8, i3 = i + 12, i4 = i + 16, i5 = i + 20,
          i6 = i + 24, i7 = i + 28;
      int p0 = sid[i];
      int p1 = sid[i1 < nm1 ? i1 : nm1];
      int p2 = sid[i2 < nm1 ? i2 : nm1];
      int p3 = sid[i3 < nm1 ? i3 : nm1];
      int p4 = sid[i4 < nm1 ? i4 : nm1];
      int p5 = sid[i5 < nm1 ? i5 : nm1];
      int p6 = sid[i6 < nm1 ? i6 : nm1];
      int p7 = sid[i7 < nm1 ? i7 : nm1];
      float4 v0 = x4[(size_t)p0 * 16 + q];
      float4 v1 = x4[(size_t)p1 * 16 + q];
      float4 v2 = x4[(size_t)p2 * 16 + q];
      float4 v3 = x4[(size_t)p3 * 16 + q];
      float4 v4 = x4[(size_t)p4 * 16 + q];
      float4 v5 = x4[(size_t)p5 * 16 + q];
      float4 v6 = x4[(size_t)p6 * 16 + q];
      float4 v7 = x4[(size_t)p7 * 16 + q];
      ax += v0.x; ay += v0.y; az += v0.z; aw += v0.w;
      if (i1 < n) { ax += v1.x; ay += v1.y; az += v1.z; aw += v1.w; }
      if (i2 < n) { ax += v2.x; ay += v2.y; az += v2.z; aw += v2.w; }
      if (i3 < n) { ax += v3.x; ay += v3.y; az += v3.z; aw += v3.w; }
      if (i4 < n) { ax += v4.x; ay += v4.y; az += v4.z; aw += v4.w; }
      if (i5 < n) { ax += v5.x; ay += v5.y; az += v5.z; aw += v5.w; }
      if (i6 < n) { ax += v6.x; ay += v6.y; az += v6.z; aw += v6.w; }
      if (i7 < n) { ax += v7.x; ay += v7.y; az += v7.z; aw += v7.w; }
    }
    // reduce the 4 g-partials within the wave
    ax += __shfl_xor(ax, 16); ax += __shfl_xor(ax, 32);
    ay += __shfl_xor(ay, 16); ay += __shfl_xor(ay, 32);
    az += __shfl_xor(az, 16); az += __shfl_xor(az, 32);
    aw += __shfl_xor(aw, 16); aw += __shfl_xor(aw, 32);
    if (g == 0) {
      float inv = 1.0f / fmaxf((float)n, 1.0f);
      mean_sacc[wv][q * 4 + 0] = ax * inv;
      mean_sacc[wv][q * 4 + 1] = ay * inv;
      mean_sacc[wv][q * 4 + 2] = az * inv;
      mean_sacc[wv][q * 4 + 3] = aw * inv;
    }
  }
  __syncthreads();

  // ---- phase 2: stage silu + bases of 8 mean rows (1 item/thread) ----
  {
    int r = tid >> 6, i = tid & 63;
    float xv = mean_sacc[r][i];
    s_silu[r][i] = silu_f(xv);
    float b[8];
    bspline8(xv, b);
    float4* dst = (float4*)&s_bases[r][i * 8];
    dst[0] = make_float4(b[0], b[1], b[2], b[3]);
    dst[1] = make_float4(b[4], b[5], b[6], b[7]);
  }
  __syncthreads();

  // ---- phase 3: kan1; (o, ih) = (tid&255, tid>>8) ----
  {
    int o = tid & 255, ih = tid >> 8;
    float acc[8];
#pragma unroll
    for (int r = 0; r < 8; ++r) acc[r] = 0.0f;
    int i0 = ih * 32;
    for (int i = i0; i < i0 + 32; ++i) {
      float wb = bwt1[i * H1_N + o];
      const float4* wp = (const float4*)&swt1[(size_t)(i * H1_N + o) * 8];
      float4 w0 = wp[0], w1 = wp[1];
#pragma unroll
      for (int r = 0; r < 8; ++r) {
        float sv = s_silu[r][i];
        const float4* bp = (const float4*)&s_bases[r][i * 8];
        float4 b0 = bp[0], b1 = bp[1];
        float a = acc[r];
        a = fmaf(sv, wb, a);
        a = fmaf(b0.x, w0.x, a); a = fmaf(b0.y, w0.y, a);
        a = fmaf(b0.z, w0.z, a); a = fmaf(b0.w, w0.w, a);
        a = fmaf(b1.x, w1.x, a); a = fmaf(b1.y, w1.y, a);
        a = fmaf(b1.z, w1.z, a); a = fmaf(b1.w, w1.w, a);
        acc[r] = a;
      }
    }
    if (ih == 0) {
#pragma unroll
      for (int r = 0; r < 8; ++r) h_lds[r][o] = acc[r];
    }
    __syncthreads();
    if (ih == 1) {
#pragma unroll
      for (int r = 0; r < 8; ++r) h_lds[r][o] += acc[r];
    }
  }
  __syncthreads();

  // ---- phase 4: kan2; (o2, rr, jh) = (tid&15, (tid>>4)&7, tid>>7) ----
  {
    int o2 = tid & 15, rr = (tid >> 4) & 7, jh = tid >> 7;  // jh in 0..3
    float acc2 = 0.0f;
    for (int ic0 = 0; ic0 < H1_N; ic0 += 64) {
      {  // stage chunk (1 item/thread)
        int r = tid >> 6, i = tid & 63;
        float xv = h_lds[r][ic0 + i];
        s_silu[r][i] = silu_f(xv);
        float b[8];
        bspline8(xv, b);
        float4* dst = (float4*)&s_bases[r][i * 8];
        dst[0] = make_float4(b[0], b[1], b[2], b[3]);
        dst[1] = make_float4(b[4], b[5], b[6], b[7]);
      }
      __syncthreads();
      int ib = jh * 16;
      for (int i = ib; i < ib + 16; ++i) {
        int gi = ic0 + i;
        float wb = bwt2[gi * NCLS_N + o2];
        const float4* wp = (const float4*)&swt2[(gi * NCLS_N + o2) * 8];
        float4 w0 = wp[0], w1 = wp[1];
        float sv = s_silu[rr][i];
        const float4* bp = (const float4*)&s_bases[rr][i * 8];
        float4 b0 = bp[0], b1 = bp[1];
        float sp = b0.x * w0.x + b0.y * w0.y + b0.z * w0.z + b0.w * w0.w
                 + b1.x * w1.x + b1.y * w1.y + b1.z * w1.z + b1.w * w1.w;
        acc2 = fmaf(sv, wb, acc2);
        acc2 += sp;
      }
      __syncthreads();
    }
    // reduce 4 jh-partials via the (dead) mean buffer
    float* sac = &mean_sacc[0][0];  // 520 floats >= 512
    sac[jh * 128 + rr * 16 + o2] = acc2;
    __syncthreads();
    if (tid < 128) {
      float s = sac[tid] + sac[128 + tid] + sac[256 + tid] + sac[384 + tid];
      out[(bid * CLPB + (tid >> 4)) * NCLS_N + (tid & 15)] = s;
    }
  }
}

extern "C" void kernel_launch(void* const* d_in, const int* in_sizes, int n_in,
                              void* d_out, int out_size, void* d_ws, size_t ws_size,
                              hipStream_t stream) {
  const float* x   = (const float*)d_in[0];
  const int*   cls = (const int*)d_in[1];
  const float* bw1 = (const float*)d_in[2];
  const float* sw1 = (const float*)d_in[3];
  const float* sc1 = (const float*)d_in[4];
  const float* bw2 = (const float*)d_in[5];
  const float* sw2 = (const float*)d_in[6];
  const float* sc2 = (const float*)d_in[7];
  float* out = (float*)d_out;

  int*   ccnt = (int*)d_ws;                     // 4096         (16 KB)
  int*   spk  = ccnt + K_CLS;                   // 4096*512     (8 MB)
  float* swt1 = (float*)(spk + K_CLS * CAP);    // 64*256*8     (512 KB)
  float* bwt1 = swt1 + C_IN * H1_N * 8;         // 64*256
  float* swt2 = bwt1 + C_IN * H1_N;             // 256*16*8     (128 KB)
  float* bwt2 = swt2 + H1_N * NCLS_N * 8;       // 256*16

  transpose_w<<<C_IN + H1_N / 2 + K_CLS / 256, 256, 0, stream>>>(
      bw1, sw1, sc1, bw2, sw2, sc2, bwt1, swt1, bwt2, swt2, ccnt);
  scatter_atomic<<<SCAT_BLOCKS, 1024, 0, stream>>>(cls, ccnt, spk);
  mega<<<K_CLS / CLPB, 512, 0, stream>>>(
      x, spk, ccnt, bwt1, swt1, bwt2, swt2, out);
}